// Round 1
// 1227.777 us; speedup vs baseline: 1.3546x; 1.3546x over previous
//
#include <hip/hip_runtime.h>
#include <hip/hip_bf16.h>

constexpr int kDIM = 768;
constexpr int kHEADS = 6;
constexpr int kLEVELS = 3;
constexpr int kPOINTS = 4;
constexpr int kHID = 192;
constexpr int kB = 4;
constexpr int kH0 = 64;
constexpr int kW0 = 64;
constexpr int kNQ = kH0 * kW0;   // 4096
constexpr int kNV = 21504;       // 128*128 + 64*64 + 32*32
constexpr int kDH = 128;         // head dim
constexpr float kEPS = 1e-6f;
constexpr int kOAW = 256;        // padded off+aw output columns (144 off + 72 aw + 40 pad)

typedef __attribute__((ext_vector_type(8))) short short8;     // 8 bf16 = 4 VGPRs (MFMA A/B frag)
typedef __attribute__((ext_vector_type(4))) float floatx4;    // MFMA C/D frag
typedef __attribute__((ext_vector_type(4))) unsigned int uintx4;

__device__ __forceinline__ float bf2f(__hip_bfloat16 x) { return __bfloat162float(x); }

// ---------------- LN -> bf16 out (used for query and feat chunks) ----------------
__global__ __launch_bounds__(256) void ln_bf16_kernel(
    const float* __restrict__ x, const float* __restrict__ g,
    const float* __restrict__ b, __hip_bfloat16* __restrict__ out)
{
  constexpr int MT = 8;
  int tid = threadIdx.x, grp = tid >> 5, lane = tid & 31;
  size_t row = (size_t)blockIdx.x * MT + grp;
  const float* xr = x + row * kDIM;
  float buf[kDIM / 32];   // 24 regs
  float s = 0.f;
#pragma unroll
  for (int i = 0; i < kDIM / 32; ++i) { float v = xr[lane + i * 32]; buf[i] = v; s += v; }
  for (int d = 16; d > 0; d >>= 1) s += __shfl_down(s, d, 32);
  float mean = __shfl(s, 0, 32) * (1.f / kDIM);
  float vs = 0.f;
#pragma unroll
  for (int i = 0; i < kDIM / 32; ++i) { float d = buf[i] - mean; vs += d * d; }
  for (int d = 16; d > 0; d >>= 1) vs += __shfl_down(vs, d, 32);
  float rstd = rsqrtf(__shfl(vs, 0, 32) * (1.f / kDIM) + kEPS);
  __hip_bfloat16* orow = out + row * kDIM;
#pragma unroll
  for (int i = 0; i < kDIM / 32; ++i) {
    int k = lane + i * 32;
    orow[k] = __float2bfloat16((buf[i] - mean) * rstd * g[k] + b[k]);
  }
}

// ---------------- W[k][n] f32 -> Wt[n][k] bf16 (768x768) ----------------
__global__ __launch_bounds__(256) void transpose_w_kernel(
    const float* __restrict__ w, __hip_bfloat16* __restrict__ wt)
{
  int t = blockIdx.x * 256 + threadIdx.x;   // n*768+k
  int n = t / kDIM, k = t % kDIM;
  wt[t] = __float2bfloat16(w[(size_t)k * kDIM + n]);
}

// ---------------- combined off_w/aw_w -> Wt[256][768] bf16 + bias[256] f32 --------
__global__ __launch_bounds__(256) void prep_offaw_w_kernel(
    const float* __restrict__ ow, const float* __restrict__ aww,
    const float* __restrict__ ob, const float* __restrict__ awb,
    __hip_bfloat16* __restrict__ wt, float* __restrict__ bias)
{
  int t = blockIdx.x * 256 + threadIdx.x;   // n*768+k, n in [0,256)
  int n = t / kDIM, k = t % kDIM;
  float v = 0.f;
  if (n < 144)       v = ow[(size_t)k * 144 + n];
  else if (n < 216)  v = aww[(size_t)k * 72 + (n - 144)];
  wt[t] = __float2bfloat16(v);
  if (t < kOAW) {
    float b = 0.f;
    if (t < 144)       b = ob[t];
    else if (t < 216)  b = awb[t - 144];
    bias[t] = b;
  }
}

// ---------------- MFMA GEMM-BT: C[M][N] = A[M][768] @ Bt[N][768]^T ----------------
// A, Bt bf16 row-major. 128x128 tile, BK=64, 256 thr = 4 waves, 4x4 16x16x32 MFMA per wave.
// XOR swizzle: LDS chunk (m, c) stores k-chunk (c ^ (m&7)); both staging and frag reads agree.
// EPI 0: outB = bf16(acc + bias)       (feat v-projection, ldc=768)
// EPI 1: outF = acc + bias + bf16 qln + f32 query   (op-projection + residuals, ldc=768)
// EPI 2: outF = acc + bias             (off/aw logits, ldc=256)
template <int EPI>
__global__ __launch_bounds__(256) void gemm_bt_kernel(
    const unsigned short* __restrict__ A, const unsigned short* __restrict__ Bt,
    const float* __restrict__ bias,
    __hip_bfloat16* __restrict__ outB,
    const __hip_bfloat16* __restrict__ qln, const float* __restrict__ query,
    float* __restrict__ outF)
{
  constexpr int K = kDIM;
  constexpr int LDC = (EPI == 2) ? kOAW : kDIM;
  __shared__ unsigned short sA[128 * 64];
  __shared__ unsigned short sB[128 * 64];
  int tid = threadIdx.x;
  int wave = tid >> 6, lane = tid & 63;
  int tm = blockIdx.x * 128, tn = blockIdx.y * 128;
  int wm = (wave & 1) * 64, wn = (wave >> 1) * 64;
  floatx4 acc[4][4] = {};

  for (int k0 = 0; k0 < K; k0 += 64) {
    __syncthreads();
#pragma unroll
    for (int i = 0; i < 4; ++i) {
      int id = i * 256 + tid;
      int m = id >> 3, c = id & 7;
      uintx4 va = *(const uintx4*)(A + (size_t)(tm + m) * K + k0 + c * 8);
      *(uintx4*)((char*)sA + m * 128 + ((c ^ (m & 7)) * 16)) = va;
      uintx4 vb = *(const uintx4*)(Bt + (size_t)(tn + m) * K + k0 + c * 8);
      *(uintx4*)((char*)sB + m * 128 + ((c ^ (m & 7)) * 16)) = vb;
    }
    __syncthreads();
#pragma unroll
    for (int s = 0; s < 2; ++s) {
      int kc = s * 4 + (lane >> 4);
      short8 af[4], bfr[4];
#pragma unroll
      for (int i = 0; i < 4; ++i) {
        int mm = wm + i * 16 + (lane & 15);
        af[i] = *(const short8*)((const char*)sA + mm * 128 + ((kc ^ (mm & 7)) * 16));
        int nn = wn + i * 16 + (lane & 15);
        bfr[i] = *(const short8*)((const char*)sB + nn * 128 + ((kc ^ (nn & 7)) * 16));
      }
#pragma unroll
      for (int i = 0; i < 4; ++i)
#pragma unroll
        for (int j = 0; j < 4; ++j)
          acc[i][j] = __builtin_amdgcn_mfma_f32_16x16x32_bf16(af[i], bfr[j], acc[i][j], 0, 0, 0);
    }
  }

  // C/D layout (m89/m91 verified): col = lane&15, row = (lane>>4)*4 + reg
  int r0 = (lane >> 4) * 4, cc = lane & 15;
#pragma unroll
  for (int i = 0; i < 4; ++i) {
    int rowb = tm + wm + i * 16 + r0;
#pragma unroll
    for (int j = 0; j < 4; ++j) {
      int col = tn + wn + j * 16 + cc;
      float bv = bias[col];
#pragma unroll
      for (int r = 0; r < 4; ++r) {
        size_t o = (size_t)(rowb + r) * LDC + col;
        float val = acc[i][j][r] + bv;
        if constexpr (EPI == 0) {
          outB[o] = __float2bfloat16(val);
        } else if constexpr (EPI == 1) {
          outF[o] = val + bf2f(qln[o]) + query[o];
        } else {
          outF[o] = val;
        }
      }
    }
  }
}

// -------- softmax over the 12 aw logits per (row, head), in place in raw buffer --------
__global__ __launch_bounds__(256) void aw_softmax_kernel(float* __restrict__ raw)
{
  int t = blockIdx.x * 256 + threadIdx.x;   // row*6+h
  int row = t / kHEADS, h = t % kHEADS;
  float* p = raw + (size_t)row * kOAW + 144 + h * 12;
  float v[12];
  float m = -1e30f;
#pragma unroll
  for (int j = 0; j < 12; ++j) { v[j] = p[j]; m = fmaxf(m, v[j]); }
  float den = 0.f;
#pragma unroll
  for (int j = 0; j < 12; ++j) { v[j] = expf(v[j] - m); den += v[j]; }
  float inv = 1.f / den;
#pragma unroll
  for (int j = 0; j < 12; ++j) p[j] = v[j] * inv;
}

// -------- K4: bilinear sampling + attention-weighted sum (bf16 out) --------
// off/aw both live in the combined raw buffer: row stride kOAW,
// off at cols [0,144), softmaxed aw at cols [144,216).
__global__ __launch_bounds__(256) void sample_kernel(
    const float* __restrict__ offaw,
    const float* __restrict__ refp, const __hip_bfloat16* __restrict__ v,
    __hip_bfloat16* __restrict__ samp)
{
  const int LH[3] = {128, 64, 32};
  const int LST[3] = {0, 16384, 20480};
  int tid = threadIdx.x;
  int bq = blockIdx.x / 3;
  int hp = blockIdx.x % 3;
  int h = hp * 2 + (tid >> 7);
  int c = tid & 127;
  int b = bq >> 12;
  const float* offr = offaw + (size_t)bq * kOAW + h * 24;
  const float* awr  = offaw + (size_t)bq * kOAW + 144 + h * 12;
  const float* refr = refp + (size_t)bq * (kLEVELS * 2);
  float acc = 0.f;
  for (int l = 0; l < kLEVELS; ++l) {
    int Wl = LH[l], Hl = LH[l];
    float rx = refr[l * 2 + 0], ry = refr[l * 2 + 1];
    const __hip_bfloat16* vbase = v + ((size_t)b * kNV + LST[l]) * kDIM + h * kDH + c;
    for (int p = 0; p < kPOINTS; ++p) {
      float xx = rx * Wl + offr[l * 8 + p * 2 + 0] - 0.5f;
      float yy = ry * Hl + offr[l * 8 + p * 2 + 1] - 0.5f;
      float x0f = floorf(xx), y0f = floorf(yy);
      int x0 = (int)x0f, y0 = (int)y0f;
      float wx = xx - x0f, wy = yy - y0f;
      float wgt = awr[l * 4 + p];
      float sv = 0.f;
#pragma unroll
      for (int cy = 0; cy < 2; ++cy) {
#pragma unroll
        for (int cx = 0; cx < 2; ++cx) {
          int xi = x0 + cx, yi = y0 + cy;
          bool valid = (xi >= 0) && (xi < Wl) && (yi >= 0) && (yi < Hl);
          int xc = min(max(xi, 0), Wl - 1), yc = min(max(yi, 0), Hl - 1);
          float cw = (cx ? wx : 1.f - wx) * (cy ? wy : 1.f - wy);
          float val = bf2f(vbase[(size_t)(yc * Wl + xc) * kDIM]);
          sv += cw * (valid ? 1.f : 0.f) * val;
        }
      }
      acc += wgt * sv;
    }
  }
  samp[(size_t)bq * kDIM + h * kDH + c] = __float2bfloat16(acc);
}

// -------- K6: y1 = LN(x)*ffn_g+ffn_b @ fc1_w + fc1_b --------
__global__ __launch_bounds__(256) void fc1_kernel(
    const float* __restrict__ x, const float* __restrict__ g,
    const float* __restrict__ bta,
    const float* __restrict__ w, const float* __restrict__ bias,
    float* __restrict__ y1)
{
  constexpr int MT = 8;
  __shared__ float a[MT][kDIM];
  int tid = threadIdx.x;
  int grp = tid >> 5, lane = tid & 31;
  size_t row = (size_t)blockIdx.x * MT + grp;
  const float* xr = x + row * kDIM;
  float s = 0.f;
  for (int k = lane; k < kDIM; k += 32) { float v = xr[k]; a[grp][k] = v; s += v; }
  for (int d = 16; d > 0; d >>= 1) s += __shfl_down(s, d, 32);
  float mean = __shfl(s, 0, 32) * (1.f / kDIM);
  float vs = 0.f;
  for (int k = lane; k < kDIM; k += 32) { float d = a[grp][k] - mean; vs += d * d; }
  for (int d = 16; d > 0; d >>= 1) vs += __shfl_down(vs, d, 32);
  float rstd = rsqrtf(__shfl(vs, 0, 32) * (1.f / kDIM) + kEPS);
  for (int k = lane; k < kDIM; k += 32)
    a[grp][k] = (a[grp][k] - mean) * rstd * g[k] + bta[k];
  __syncthreads();
  if (tid < kHID) {
    float acc[MT] = {};
    for (int k = 0; k < kDIM; ++k) {
      float wv = w[(size_t)k * kHID + tid];
#pragma unroll
      for (int r = 0; r < MT; ++r) acc[r] += a[r][k] * wv;
    }
    float bv = bias[tid];
    size_t row0 = (size_t)blockIdx.x * MT;
    for (int r = 0; r < MT; ++r) y1[(row0 + r) * kHID + tid] = acc[r] + bv;
  }
}

// -------- K7: y2 = gelu(dwconv3x3(y1) + dw_b) --------
__global__ __launch_bounds__(256) void dwconv_gelu_kernel(
    const float* __restrict__ y1, const float* __restrict__ w,
    const float* __restrict__ bias, float* __restrict__ y2)
{
  int idx = blockIdx.x * 256 + threadIdx.x;
  int c = idx % kHID;
  int j = (idx / kHID) % kW0;
  int i = (idx / (kHID * kW0)) % kH0;
  int b = idx / (kHID * kW0 * kH0);
  float s = bias[c];
#pragma unroll
  for (int ky = 0; ky < 3; ++ky) {
    int yi = i + ky - 1;
    if (yi < 0 || yi >= kH0) continue;
#pragma unroll
    for (int kx = 0; kx < 3; ++kx) {
      int xj = j + kx - 1;
      if (xj < 0 || xj >= kW0) continue;
      s += y1[(((size_t)b * kH0 + yi) * kW0 + xj) * kHID + c] * w[(ky * 3 + kx) * kHID + c];
    }
  }
  y2[idx] = 0.5f * s * (1.f + erff(s * 0.70710678118654752440f));
}

// -------- K8: out = x + y2 @ fc2_w + fc2_b  (f32 out) --------
__global__ __launch_bounds__(256) void fc2_out_kernel(
    const float* __restrict__ y2, const float* __restrict__ w,
    const float* __restrict__ bias, const float* __restrict__ x,
    float* __restrict__ out)
{
  constexpr int MT = 8;
  __shared__ float a[MT][kHID];
  int tid = threadIdx.x;
  size_t row0 = (size_t)blockIdx.x * MT;
  for (int i = tid; i < MT * kHID; i += 256) a[i / kHID][i % kHID] = y2[row0 * kHID + i];
  __syncthreads();
  float acc[MT][3] = {};
  for (int k = 0; k < kHID; ++k) {
    float w0 = w[(size_t)k * kDIM + tid];
    float w1 = w[(size_t)k * kDIM + tid + 256];
    float w2 = w[(size_t)k * kDIM + tid + 512];
#pragma unroll
    for (int r = 0; r < MT; ++r) {
      float av = a[r][k];
      acc[r][0] += av * w0; acc[r][1] += av * w1; acc[r][2] += av * w2;
    }
  }
  float b0 = bias[tid], b1 = bias[tid + 256], b2 = bias[tid + 512];
  for (int r = 0; r < MT; ++r) {
    size_t o = (row0 + r) * kDIM;
    out[o + tid]       = x[o + tid]       + acc[r][0] + b0;
    out[o + tid + 256] = x[o + tid + 256] + acc[r][1] + b1;
    out[o + tid + 512] = x[o + tid + 512] + acc[r][2] + b2;
  }
}

extern "C" void kernel_launch(void* const* d_in, const int* in_sizes, int n_in,
                              void* d_out, int out_size, void* d_ws, size_t ws_size,
                              hipStream_t stream)
{
  const float* query = (const float*)d_in[0];
  const float* refp  = (const float*)d_in[1];
  const float* feat  = (const float*)d_in[2];
  const float* qn_g  = (const float*)d_in[7];
  const float* qn_b  = (const float*)d_in[8];
  const float* fn_g  = (const float*)d_in[9];
  const float* fn_b  = (const float*)d_in[10];
  const float* off_w = (const float*)d_in[11];
  const float* off_b = (const float*)d_in[12];
  const float* aw_w  = (const float*)d_in[13];
  const float* aw_b  = (const float*)d_in[14];
  const float* vp_w  = (const float*)d_in[15];
  const float* vp_b  = (const float*)d_in[16];
  const float* op_w  = (const float*)d_in[17];
  const float* op_b  = (const float*)d_in[18];
  const float* ffn_g = (const float*)d_in[19];
  const float* ffn_b = (const float*)d_in[20];
  const float* fc1_w = (const float*)d_in[21];
  const float* fc1_b = (const float*)d_in[22];
  const float* dw_w  = (const float*)d_in[23];
  const float* dw_b  = (const float*)d_in[24];
  const float* fc2_w = (const float*)d_in[25];
  const float* fc2_b = (const float*)d_in[26];

  char* ws = (char*)d_ws;
  // workspace (total 217,711,616 B; known-safe budget 221,773,824):
  // R0 @ 0 (66,060,288):
  //   phase A: a_ln bf16 chunk (43008x768)           [ln_feat -> gemm, per chunk]
  //   phase B: q_ln bf16 @0 (25,165,824)             [ln_q -> offaw gemm + opproj epi]
  //            samp bf16 @39,321,600 (25,165,824)    [sample -> opproj]
  // V  @ 66,060,288 (132,120,576):
  //   phase A/B: v bf16 (86016x768)                  [gemm -> sample]
  //   after sample: x f32 @66,060,288 (50,331,648)   [opproj -> fc2]
  //                 y1 f32 @116,391,936 (12,582,912) [fc1 -> dwconv]
  //                 y2 f32 @128,974,848 (12,582,912) [dwconv -> fc2]
  // W  @ 198,180,864: vp_w_t bf16 (1,179,648) ; op_w_t bf16 @199,360,512 (1,179,648)
  // OA @ 200,540,160: offaw raw f32 (16384x256 = 16,777,216)
  //    @ 217,317,376: offaw_wt bf16 (256x768 = 393,216)
  //    @ 217,710,592: offaw_bias f32 (1,024)
  constexpr size_t kWsNeeded = 217711616ull;
  if (ws_size < kWsNeeded) return;

  __hip_bfloat16* a_ln     = (__hip_bfloat16*)(ws + 0);
  __hip_bfloat16* q_ln     = (__hip_bfloat16*)(ws + 0);
  __hip_bfloat16* samp     = (__hip_bfloat16*)(ws + 39321600ull);
  __hip_bfloat16* v        = (__hip_bfloat16*)(ws + 66060288ull);
  float*          x        = (float*)(ws + 66060288ull);
  float*          y1       = (float*)(ws + 116391936ull);
  float*          y2       = (float*)(ws + 128974848ull);
  __hip_bfloat16* vp_w_t   = (__hip_bfloat16*)(ws + 198180864ull);
  __hip_bfloat16* op_w_t   = (__hip_bfloat16*)(ws + 199360512ull);
  float*          oa_raw   = (float*)(ws + 200540160ull);
  __hip_bfloat16* oa_wt    = (__hip_bfloat16*)(ws + 217317376ull);
  float*          oa_bias  = (float*)(ws + 217710592ull);

  constexpr int NROWQ = kB * kNQ;          // 16384
  constexpr int NROWV = kB * kNV;          // 86016
  constexpr int CHUNK = NROWV / 2;         // 43008

  // weight prep
  transpose_w_kernel<<<(kDIM * kDIM) / 256, 256, 0, stream>>>(vp_w, vp_w_t);
  transpose_w_kernel<<<(kDIM * kDIM) / 256, 256, 0, stream>>>(op_w, op_w_t);
  prep_offaw_w_kernel<<<(kOAW * kDIM) / 256, 256, 0, stream>>>(
      off_w, aw_w, off_b, aw_b, oa_wt, oa_bias);

  // phase A: v = LN(feat) @ vp_w + vp_b, two M-chunks through the shared a_ln buffer
  for (int c = 0; c < 2; ++c) {
    ln_bf16_kernel<<<CHUNK / 8, 256, 0, stream>>>(
        feat + (size_t)c * CHUNK * kDIM, fn_g, fn_b, a_ln);
    gemm_bt_kernel<0><<<dim3(CHUNK / 128, kDIM / 128), 256, 0, stream>>>(
        (const unsigned short*)a_ln, (const unsigned short*)vp_w_t, vp_b,
        v + (size_t)c * CHUNK * kDIM, nullptr, nullptr, nullptr);
  }

  // phase B
  ln_bf16_kernel<<<NROWQ / 8, 256, 0, stream>>>(query, qn_g, qn_b, q_ln);
  // off/aw logits via MFMA: raw[16384][256] = q_ln @ oa_wt^T + oa_bias
  gemm_bt_kernel<2><<<dim3(NROWQ / 128, kOAW / 128), 256, 0, stream>>>(
      (const unsigned short*)q_ln, (const unsigned short*)oa_wt, oa_bias,
      nullptr, nullptr, nullptr, oa_raw);
  aw_softmax_kernel<<<(NROWQ * kHEADS) / 256, 256, 0, stream>>>(oa_raw);
  sample_kernel<<<NROWQ * 3, 256, 0, stream>>>(oa_raw, refp, v, samp);
  gemm_bt_kernel<1><<<dim3(NROWQ / 128, kDIM / 128), 256, 0, stream>>>(
      (const unsigned short*)samp, (const unsigned short*)op_w_t, op_b,
      nullptr, q_ln, query, x);
  fc1_kernel<<<NROWQ / 8, 256, 0, stream>>>(x, ffn_g, ffn_b, fc1_w, fc1_b, y1);
  dwconv_gelu_kernel<<<(NROWQ * kHID) / 256, 256, 0, stream>>>(y1, dw_w, dw_b, y2);
  fc2_out_kernel<<<NROWQ / 8, 256, 0, stream>>>(y2, fc2_w, fc2_b, x, (float*)d_out);
}

// Round 2
// 876.931 us; speedup vs baseline: 1.8965x; 1.4001x over previous
//
#include <hip/hip_runtime.h>
#include <hip/hip_bf16.h>

constexpr int kDIM = 768;
constexpr int kHEADS = 6;
constexpr int kLEVELS = 3;
constexpr int kPOINTS = 4;
constexpr int kHID = 192;
constexpr int kB = 4;
constexpr int kH0 = 64;
constexpr int kW0 = 64;
constexpr int kNQ = kH0 * kW0;   // 4096
constexpr int kNV = 21504;       // 128*128 + 64*64 + 32*32
constexpr int kDH = 128;         // head dim
constexpr float kEPS = 1e-6f;
constexpr int kOAW = 256;        // padded off+aw / fc1 output columns

typedef __attribute__((ext_vector_type(8))) short short8;     // 8 bf16 = 4 VGPRs (MFMA A/B frag)
typedef __attribute__((ext_vector_type(4))) float floatx4;    // MFMA C/D frag
typedef __attribute__((ext_vector_type(4))) unsigned int uintx4;

__device__ __forceinline__ float bf2f(__hip_bfloat16 x) { return __bfloat162float(x); }
__device__ __forceinline__ float bfu2f(unsigned short u) { return __uint_as_float(((unsigned)u) << 16); }
__device__ __forceinline__ unsigned short f2bfu(float f) {
  __hip_bfloat16 h = __float2bfloat16(f);
  return *reinterpret_cast<unsigned short*>(&h);
}

// ---------------- LN -> bf16 out (query, feat chunks, ffn-LN of x) ----------------
__global__ __launch_bounds__(256) void ln_bf16_kernel(
    const float* __restrict__ x, const float* __restrict__ g,
    const float* __restrict__ b, __hip_bfloat16* __restrict__ out)
{
  constexpr int MT = 8;
  int tid = threadIdx.x, grp = tid >> 5, lane = tid & 31;
  size_t row = (size_t)blockIdx.x * MT + grp;
  const float* xr = x + row * kDIM;
  float buf[kDIM / 32];   // 24 regs
  float s = 0.f;
#pragma unroll
  for (int i = 0; i < kDIM / 32; ++i) { float v = xr[lane + i * 32]; buf[i] = v; s += v; }
  for (int d = 16; d > 0; d >>= 1) s += __shfl_down(s, d, 32);
  float mean = __shfl(s, 0, 32) * (1.f / kDIM);
  float vs = 0.f;
#pragma unroll
  for (int i = 0; i < kDIM / 32; ++i) { float d = buf[i] - mean; vs += d * d; }
  for (int d = 16; d > 0; d >>= 1) vs += __shfl_down(vs, d, 32);
  float rstd = rsqrtf(__shfl(vs, 0, 32) * (1.f / kDIM) + kEPS);
  __hip_bfloat16* orow = out + row * kDIM;
#pragma unroll
  for (int i = 0; i < kDIM / 32; ++i) {
    int k = lane + i * 32;
    orow[k] = __float2bfloat16((buf[i] - mean) * rstd * g[k] + b[k]);
  }
}

// ---------------- W[k][n] f32 -> Wt[n][k] bf16 (768x768) ----------------
__global__ __launch_bounds__(256) void transpose_w_kernel(
    const float* __restrict__ w, __hip_bfloat16* __restrict__ wt)
{
  int t = blockIdx.x * 256 + threadIdx.x;   // n*768+k
  int n = t / kDIM, k = t % kDIM;
  wt[t] = __float2bfloat16(w[(size_t)k * kDIM + n]);
}

// ------- generic W[K][N] f32 -> Wt[NPAD][K] bf16 (rows >= N zero) + bias pad -------
template <int K, int N, int NPAD>
__global__ __launch_bounds__(256) void prep_wt_kernel(
    const float* __restrict__ w, const float* __restrict__ b,
    __hip_bfloat16* __restrict__ wt, float* __restrict__ bp)
{
  int t = blockIdx.x * 256 + threadIdx.x;   // n*K + k, n in [0, NPAD)
  int n = t / K, k = t % K;
  float v = (n < N) ? w[(size_t)k * N + n] : 0.f;
  wt[t] = __float2bfloat16(v);
  if (bp != nullptr && t < NPAD) bp[t] = (t < N) ? b[t] : 0.f;
}

// ---------------- combined off_w/aw_w -> Wt[256][768] bf16 + bias[256] f32 --------
__global__ __launch_bounds__(256) void prep_offaw_w_kernel(
    const float* __restrict__ ow, const float* __restrict__ aww,
    const float* __restrict__ ob, const float* __restrict__ awb,
    __hip_bfloat16* __restrict__ wt, float* __restrict__ bias)
{
  int t = blockIdx.x * 256 + threadIdx.x;   // n*768+k, n in [0,256)
  int n = t / kDIM, k = t % kDIM;
  float v = 0.f;
  if (n < 144)       v = ow[(size_t)k * 144 + n];
  else if (n < 216)  v = aww[(size_t)k * 72 + (n - 144)];
  wt[t] = __float2bfloat16(v);
  if (t < kOAW) {
    float b = 0.f;
    if (t < 144)       b = ob[t];
    else if (t < 216)  b = awb[t - 144];
    bias[t] = b;
  }
}

// ---------------- MFMA GEMM-BT: C[M][N] = A[M][KK] @ Bt[N][KK]^T ----------------
// A, Bt bf16 row-major. 128x128 tile, BK=64, 256 thr = 4 waves, 4x4 16x16x32 MFMA per wave.
// XOR swizzle: LDS chunk (m, c) stores k-chunk (c ^ (m&7)); both staging and frag reads agree.
// EPI 0: outB = bf16(acc + bias)                    (feat v-projection, ldc=768)
// EPI 1: outF = acc + bias + bf16 qln + f32 query   (op-projection + residuals, ldc=768)
// EPI 2: outF = acc + bias                          (off/aw logits & fc1, ldc=256)
// EPI 3: outF = acc + bias + query                  (fc2 + residual x, ldc=768)
template <int EPI, int KK>
__global__ __launch_bounds__(256) void gemm_bt_kernel(
    const unsigned short* __restrict__ A, const unsigned short* __restrict__ Bt,
    const float* __restrict__ bias,
    __hip_bfloat16* __restrict__ outB,
    const __hip_bfloat16* __restrict__ qln, const float* __restrict__ query,
    float* __restrict__ outF)
{
  constexpr int K = KK;
  constexpr int LDC = (EPI == 2) ? kOAW : kDIM;
  __shared__ unsigned short sA[128 * 64];
  __shared__ unsigned short sB[128 * 64];
  int tid = threadIdx.x;
  int wave = tid >> 6, lane = tid & 63;
  int tm = blockIdx.x * 128, tn = blockIdx.y * 128;
  int wm = (wave & 1) * 64, wn = (wave >> 1) * 64;
  floatx4 acc[4][4] = {};

  for (int k0 = 0; k0 < K; k0 += 64) {
    __syncthreads();
#pragma unroll
    for (int i = 0; i < 4; ++i) {
      int id = i * 256 + tid;
      int m = id >> 3, c = id & 7;
      uintx4 va = *(const uintx4*)(A + (size_t)(tm + m) * K + k0 + c * 8);
      *(uintx4*)((char*)sA + m * 128 + ((c ^ (m & 7)) * 16)) = va;
      uintx4 vb = *(const uintx4*)(Bt + (size_t)(tn + m) * K + k0 + c * 8);
      *(uintx4*)((char*)sB + m * 128 + ((c ^ (m & 7)) * 16)) = vb;
    }
    __syncthreads();
#pragma unroll
    for (int s = 0; s < 2; ++s) {
      int kc = s * 4 + (lane >> 4);
      short8 af[4], bfr[4];
#pragma unroll
      for (int i = 0; i < 4; ++i) {
        int mm = wm + i * 16 + (lane & 15);
        af[i] = *(const short8*)((const char*)sA + mm * 128 + ((kc ^ (mm & 7)) * 16));
        int nn = wn + i * 16 + (lane & 15);
        bfr[i] = *(const short8*)((const char*)sB + nn * 128 + ((kc ^ (nn & 7)) * 16));
      }
#pragma unroll
      for (int i = 0; i < 4; ++i)
#pragma unroll
        for (int j = 0; j < 4; ++j)
          acc[i][j] = __builtin_amdgcn_mfma_f32_16x16x32_bf16(af[i], bfr[j], acc[i][j], 0, 0, 0);
    }
  }

  // C/D layout (m89/m91 verified): col = lane&15, row = (lane>>4)*4 + reg
  int r0 = (lane >> 4) * 4, cc = lane & 15;
#pragma unroll
  for (int i = 0; i < 4; ++i) {
    int rowb = tm + wm + i * 16 + r0;
#pragma unroll
    for (int j = 0; j < 4; ++j) {
      int col = tn + wn + j * 16 + cc;
      float bv = bias[col];
#pragma unroll
      for (int r = 0; r < 4; ++r) {
        size_t o = (size_t)(rowb + r) * LDC + col;
        float val = acc[i][j][r] + bv;
        if constexpr (EPI == 0) {
          outB[o] = __float2bfloat16(val);
        } else if constexpr (EPI == 1) {
          outF[o] = val + bf2f(qln[o]) + query[o];
        } else if constexpr (EPI == 2) {
          outF[o] = val;
        } else {
          outF[o] = val + query[o];
        }
      }
    }
  }
}

// -------- softmax over the 12 aw logits per (row, head), in place in raw buffer --------
__global__ __launch_bounds__(256) void aw_softmax_kernel(float* __restrict__ raw)
{
  int t = blockIdx.x * 256 + threadIdx.x;   // row*6+h
  int row = t / kHEADS, h = t % kHEADS;
  float* p = raw + (size_t)row * kOAW + 144 + h * 12;
  float v[12];
  float m = -1e30f;
#pragma unroll
  for (int j = 0; j < 12; ++j) { v[j] = p[j]; m = fmaxf(m, v[j]); }
  float den = 0.f;
#pragma unroll
  for (int j = 0; j < 12; ++j) { v[j] = expf(v[j] - m); den += v[j]; }
  float inv = 1.f / den;
#pragma unroll
  for (int j = 0; j < 12; ++j) p[j] = v[j] * inv;
}

// -------- K4: bilinear sampling + attention-weighted sum (bf16 out) --------
// One block per (b,q). Threads 0..71 precompute the 72 (head,level,point) corner
// descriptors (element offset + folded weight valid*cw*wgt) into LDS; then 192
// threads each own 4 channels (h = tid>>5, c0 = (tid&31)*4) doing pure
// ushort4-load + convert + fma. off/aw live in the combined raw buffer:
// row stride kOAW, off at cols [0,144), softmaxed aw at cols [144,216).
__global__ __launch_bounds__(192) void sample_kernel(
    const float* __restrict__ offaw,
    const float* __restrict__ refp, const __hip_bfloat16* __restrict__ v,
    __hip_bfloat16* __restrict__ samp)
{
  __shared__ int   idx_s[72][4];
  __shared__ float w_s[72][4];
  int bq = blockIdx.x;
  int b = bq >> 12;
  int tid = threadIdx.x;

  if (tid < 72) {
    const int LH[3] = {128, 64, 32};
    const int LST[3] = {0, 16384, 20480};
    int h2 = tid / 12, j = tid % 12, l = j >> 2, p = j & 3;
    int Wl = LH[l];
    const float* base = offaw + (size_t)bq * kOAW;
    float rx = refp[(size_t)bq * 6 + l * 2 + 0];
    float ry = refp[(size_t)bq * 6 + l * 2 + 1];
    float ox = base[h2 * 24 + l * 8 + p * 2 + 0];
    float oy = base[h2 * 24 + l * 8 + p * 2 + 1];
    float wgt = base[144 + h2 * 12 + l * 4 + p];
    float xx = rx * Wl + ox - 0.5f;
    float yy = ry * Wl + oy - 0.5f;
    float x0f = floorf(xx), y0f = floorf(yy);
    int x0 = (int)x0f, y0 = (int)y0f;
    float wx = xx - x0f, wy = yy - y0f;
#pragma unroll
    for (int cy = 0; cy < 2; ++cy) {
#pragma unroll
      for (int cx = 0; cx < 2; ++cx) {
        int xi = x0 + cx, yi = y0 + cy;
        bool valid = (xi >= 0) && (xi < Wl) && (yi >= 0) && (yi < Wl);
        int xc = min(max(xi, 0), Wl - 1), yc = min(max(yi, 0), Wl - 1);
        float cw = (cx ? wx : 1.f - wx) * (cy ? wy : 1.f - wy);
        idx_s[tid][cy * 2 + cx] = (LST[l] + yc * Wl + xc) * kDIM;
        w_s[tid][cy * 2 + cx] = valid ? cw * wgt : 0.f;
      }
    }
  }
  __syncthreads();

  int h = tid >> 5, c0 = (tid & 31) * 4;
  const __hip_bfloat16* vb = v + (size_t)b * kNV * kDIM + h * kDH + c0;
  float a0 = 0.f, a1 = 0.f, a2 = 0.f, a3 = 0.f;
#pragma unroll
  for (int j = 0; j < 12; ++j) {
    int t = h * 12 + j;
    int4 ii = *(const int4*)idx_s[t];
    float4 ww = *(const float4*)w_s[t];
#pragma unroll
    for (int k = 0; k < 4; ++k) {
      int idx = (k == 0) ? ii.x : (k == 1) ? ii.y : (k == 2) ? ii.z : ii.w;
      float wv = (k == 0) ? ww.x : (k == 1) ? ww.y : (k == 2) ? ww.z : ww.w;
      ushort4 uv = *(const ushort4*)(vb + idx);
      a0 += wv * bfu2f(uv.x);
      a1 += wv * bfu2f(uv.y);
      a2 += wv * bfu2f(uv.z);
      a3 += wv * bfu2f(uv.w);
    }
  }
  ushort4 ov;
  ov.x = f2bfu(a0); ov.y = f2bfu(a1); ov.z = f2bfu(a2); ov.w = f2bfu(a3);
  *(ushort4*)(samp + (size_t)bq * kDIM + h * kDH + c0) = ov;
}

// -------- K7: y2 = bf16(gelu(dwconv3x3(y1p) + dw_b)), y1p has row stride 256 --------
__global__ __launch_bounds__(256) void dwconv_gelu_kernel(
    const float* __restrict__ y1, const float* __restrict__ w,
    const float* __restrict__ bias, __hip_bfloat16* __restrict__ y2)
{
  int idx = blockIdx.x * 256 + threadIdx.x;
  int c = idx % kHID;
  int sp = idx / kHID;
  int j = sp % kW0;
  int i = (sp / kW0) % kH0;
  int b = sp / (kW0 * kH0);
  float s = bias[c];
#pragma unroll
  for (int ky = 0; ky < 3; ++ky) {
    int yi = i + ky - 1;
    if (yi < 0 || yi >= kH0) continue;
#pragma unroll
    for (int kx = 0; kx < 3; ++kx) {
      int xj = j + kx - 1;
      if (xj < 0 || xj >= kW0) continue;
      s += y1[(((size_t)b * kH0 + yi) * kW0 + xj) * kOAW + c] * w[(ky * 3 + kx) * kHID + c];
    }
  }
  float gl = 0.5f * s * (1.f + erff(s * 0.70710678118654752440f));
  y2[idx] = __float2bfloat16(gl);
}

extern "C" void kernel_launch(void* const* d_in, const int* in_sizes, int n_in,
                              void* d_out, int out_size, void* d_ws, size_t ws_size,
                              hipStream_t stream)
{
  const float* query = (const float*)d_in[0];
  const float* refp  = (const float*)d_in[1];
  const float* feat  = (const float*)d_in[2];
  const float* qn_g  = (const float*)d_in[7];
  const float* qn_b  = (const float*)d_in[8];
  const float* fn_g  = (const float*)d_in[9];
  const float* fn_b  = (const float*)d_in[10];
  const float* off_w = (const float*)d_in[11];
  const float* off_b = (const float*)d_in[12];
  const float* aw_w  = (const float*)d_in[13];
  const float* aw_b  = (const float*)d_in[14];
  const float* vp_w  = (const float*)d_in[15];
  const float* vp_b  = (const float*)d_in[16];
  const float* op_w  = (const float*)d_in[17];
  const float* op_b  = (const float*)d_in[18];
  const float* ffn_g = (const float*)d_in[19];
  const float* ffn_b = (const float*)d_in[20];
  const float* fc1_w = (const float*)d_in[21];
  const float* fc1_b = (const float*)d_in[22];
  const float* dw_w  = (const float*)d_in[23];
  const float* dw_b  = (const float*)d_in[24];
  const float* fc2_w = (const float*)d_in[25];
  const float* fc2_b = (const float*)d_in[26];

  char* ws = (char*)d_ws;
  // workspace (total 218,400,768 B; known-safe budget 221,773,824):
  // R0 @ 0 (66,060,288), time-multiplexed:
  //   phase A: a_ln bf16 chunk (43008x768)            [ln_feat -> gemm, per chunk]
  //   phase B: q_ln bf16 @0 (25,165,824)              [ln_q -> offaw gemm + opproj epi]
  //            samp bf16 @39,321,600 (25,165,824)     [sample -> opproj]
  //   phase C (after opproj): x_ln bf16 @0 (25,165,824)      [ln_ffn -> fc1 gemm]
  //            y1p f32 @25,165,824 (16,777,216, ldc 256)     [fc1 -> dwconv]
  //            y2 bf16 @41,943,040 (6,291,456)               [dwconv -> fc2]
  // V  @ 66,060,288 (132,120,576):
  //   phase A/B: v bf16 (86016x768)                   [gemm -> sample]
  //   phase C: x f32 @66,060,288 (50,331,648)         [opproj -> fc2 residual]
  // W  @ 198,180,864: vp_w_t bf16 (1,179,648) ; op_w_t bf16 @199,360,512 (1,179,648)
  // OA @ 200,540,160: offaw raw f32 (16384x256 = 16,777,216)
  //    @ 217,317,376: offaw_wt bf16 (393,216)
  //    @ 217,710,592: offaw_bias f32 (1,024)
  // FFN @ 217,711,616: fc1_wt bf16 [256][768] (393,216)
  //     @ 218,104,832: fc1_bp f32 [256] (1,024)
  //     @ 218,105,856: fc2_wt bf16 [768][192] (294,912) -> ends 218,400,768
  constexpr size_t kWsNeeded = 218400768ull;
  if (ws_size < kWsNeeded) return;

  __hip_bfloat16* a_ln     = (__hip_bfloat16*)(ws + 0);
  __hip_bfloat16* q_ln     = (__hip_bfloat16*)(ws + 0);
  __hip_bfloat16* x_ln     = (__hip_bfloat16*)(ws + 0);
  float*          y1p      = (float*)(ws + 25165824ull);
  __hip_bfloat16* samp     = (__hip_bfloat16*)(ws + 39321600ull);
  __hip_bfloat16* y2       = (__hip_bfloat16*)(ws + 41943040ull);
  __hip_bfloat16* v        = (__hip_bfloat16*)(ws + 66060288ull);
  float*          x        = (float*)(ws + 66060288ull);
  __hip_bfloat16* vp_w_t   = (__hip_bfloat16*)(ws + 198180864ull);
  __hip_bfloat16* op_w_t   = (__hip_bfloat16*)(ws + 199360512ull);
  float*          oa_raw   = (float*)(ws + 200540160ull);
  __hip_bfloat16* oa_wt    = (__hip_bfloat16*)(ws + 217317376ull);
  float*          oa_bias  = (float*)(ws + 217710592ull);
  __hip_bfloat16* fc1_wt   = (__hip_bfloat16*)(ws + 217711616ull);
  float*          fc1_bp   = (float*)(ws + 218104832ull);
  __hip_bfloat16* fc2_wt   = (__hip_bfloat16*)(ws + 218105856ull);

  constexpr int NROWQ = kB * kNQ;          // 16384
  constexpr int NROWV = kB * kNV;          // 86016
  constexpr int CHUNK = NROWV / 2;         // 43008

  // weight prep
  transpose_w_kernel<<<(kDIM * kDIM) / 256, 256, 0, stream>>>(vp_w, vp_w_t);
  transpose_w_kernel<<<(kDIM * kDIM) / 256, 256, 0, stream>>>(op_w, op_w_t);
  prep_offaw_w_kernel<<<(kOAW * kDIM) / 256, 256, 0, stream>>>(
      off_w, aw_w, off_b, aw_b, oa_wt, oa_bias);
  prep_wt_kernel<768, 192, 256><<<(256 * 768) / 256, 256, 0, stream>>>(
      fc1_w, fc1_b, fc1_wt, fc1_bp);
  prep_wt_kernel<192, 768, 768><<<(768 * 192) / 256, 256, 0, stream>>>(
      fc2_w, nullptr, fc2_wt, nullptr);

  // phase A: v = LN(feat) @ vp_w + vp_b, two M-chunks through the shared a_ln buffer
  for (int c = 0; c < 2; ++c) {
    ln_bf16_kernel<<<CHUNK / 8, 256, 0, stream>>>(
        feat + (size_t)c * CHUNK * kDIM, fn_g, fn_b, a_ln);
    gemm_bt_kernel<0, kDIM><<<dim3(CHUNK / 128, kDIM / 128), 256, 0, stream>>>(
        (const unsigned short*)a_ln, (const unsigned short*)vp_w_t, vp_b,
        v + (size_t)c * CHUNK * kDIM, nullptr, nullptr, nullptr);
  }

  // phase B
  ln_bf16_kernel<<<NROWQ / 8, 256, 0, stream>>>(query, qn_g, qn_b, q_ln);
  gemm_bt_kernel<2, kDIM><<<dim3(NROWQ / 128, kOAW / 128), 256, 0, stream>>>(
      (const unsigned short*)q_ln, (const unsigned short*)oa_wt, oa_bias,
      nullptr, nullptr, nullptr, oa_raw);
  aw_softmax_kernel<<<(NROWQ * kHEADS) / 256, 256, 0, stream>>>(oa_raw);
  sample_kernel<<<NROWQ, 192, 0, stream>>>(oa_raw, refp, v, samp);
  gemm_bt_kernel<1, kDIM><<<dim3(NROWQ / 128, kDIM / 128), 256, 0, stream>>>(
      (const unsigned short*)samp, (const unsigned short*)op_w_t, op_b,
      nullptr, q_ln, query, x);

  // phase C: FFN, all matmuls via MFMA
  ln_bf16_kernel<<<NROWQ / 8, 256, 0, stream>>>(x, ffn_g, ffn_b, x_ln);
  gemm_bt_kernel<2, kDIM><<<dim3(NROWQ / 128, kOAW / 128), 256, 0, stream>>>(
      (const unsigned short*)x_ln, (const unsigned short*)fc1_wt, fc1_bp,
      nullptr, nullptr, nullptr, y1p);
  dwconv_gelu_kernel<<<(NROWQ * kHID) / 256, 256, 0, stream>>>(y1p, dw_w, dw_b, y2);
  gemm_bt_kernel<3, kHID><<<dim3(NROWQ / 128, kDIM / 128), 256, 0, stream>>>(
      (const unsigned short*)y2, (const unsigned short*)fc2_wt, fc2_b,
      nullptr, nullptr, x, (float*)d_out);
}

// Round 3
// 869.728 us; speedup vs baseline: 1.9122x; 1.0083x over previous
//
#include <hip/hip_runtime.h>
#include <hip/hip_bf16.h>

constexpr int kDIM = 768;
constexpr int kHEADS = 6;
constexpr int kLEVELS = 3;
constexpr int kPOINTS = 4;
constexpr int kHID = 192;
constexpr int kB = 4;
constexpr int kH0 = 64;
constexpr int kW0 = 64;
constexpr int kNQ = kH0 * kW0;   // 4096
constexpr int kNV = 21504;       // 128*128 + 64*64 + 32*32
constexpr int kDH = 128;         // head dim
constexpr float kEPS = 1e-6f;
constexpr int kOAW = 256;        // padded off+aw / fc1 output columns

typedef __attribute__((ext_vector_type(8))) short short8;     // 8 bf16 = 4 VGPRs (MFMA A/B frag)
typedef __attribute__((ext_vector_type(4))) float floatx4;    // MFMA C/D frag
typedef __attribute__((ext_vector_type(4))) unsigned int uintx4;

__device__ __forceinline__ float bf2f(__hip_bfloat16 x) { return __bfloat162float(x); }
__device__ __forceinline__ float bflo2f(unsigned int u) { return __uint_as_float(u << 16); }
__device__ __forceinline__ float bfhi2f(unsigned int u) { return __uint_as_float(u & 0xffff0000u); }
__device__ __forceinline__ unsigned short f2bfu(float f) {
  __hip_bfloat16 h = __float2bfloat16(f);
  return *reinterpret_cast<unsigned short*>(&h);
}

#define GLD_LDS16(g, l) \
  __builtin_amdgcn_global_load_lds( \
      (const __attribute__((address_space(1))) void*)(g), \
      (__attribute__((address_space(3))) void*)(l), 16, 0, 0)

// ---------------- LN -> bf16 out (query, feat chunks, ffn-LN of x) ----------------
__global__ __launch_bounds__(256) void ln_bf16_kernel(
    const float* __restrict__ x, const float* __restrict__ g,
    const float* __restrict__ b, __hip_bfloat16* __restrict__ out)
{
  constexpr int MT = 8;
  int tid = threadIdx.x, grp = tid >> 5, lane = tid & 31;
  size_t row = (size_t)blockIdx.x * MT + grp;
  const float* xr = x + row * kDIM;
  float buf[kDIM / 32];   // 24 regs
  float s = 0.f;
#pragma unroll
  for (int i = 0; i < kDIM / 32; ++i) { float v = xr[lane + i * 32]; buf[i] = v; s += v; }
  for (int d = 16; d > 0; d >>= 1) s += __shfl_down(s, d, 32);
  float mean = __shfl(s, 0, 32) * (1.f / kDIM);
  float vs = 0.f;
#pragma unroll
  for (int i = 0; i < kDIM / 32; ++i) { float d = buf[i] - mean; vs += d * d; }
  for (int d = 16; d > 0; d >>= 1) vs += __shfl_down(vs, d, 32);
  float rstd = rsqrtf(__shfl(vs, 0, 32) * (1.f / kDIM) + kEPS);
  __hip_bfloat16* orow = out + row * kDIM;
#pragma unroll
  for (int i = 0; i < kDIM / 32; ++i) {
    int k = lane + i * 32;
    orow[k] = __float2bfloat16((buf[i] - mean) * rstd * g[k] + b[k]);
  }
}

// ---------------- W[k][n] f32 -> Wt[n][k] bf16 (768x768) ----------------
__global__ __launch_bounds__(256) void transpose_w_kernel(
    const float* __restrict__ w, __hip_bfloat16* __restrict__ wt)
{
  int t = blockIdx.x * 256 + threadIdx.x;   // n*768+k
  int n = t / kDIM, k = t % kDIM;
  wt[t] = __float2bfloat16(w[(size_t)k * kDIM + n]);
}

// ------- generic W[K][N] f32 -> Wt[NPAD][K] bf16 (rows >= N zero) + bias pad -------
template <int K, int N, int NPAD>
__global__ __launch_bounds__(256) void prep_wt_kernel(
    const float* __restrict__ w, const float* __restrict__ b,
    __hip_bfloat16* __restrict__ wt, float* __restrict__ bp)
{
  int t = blockIdx.x * 256 + threadIdx.x;   // n*K + k, n in [0, NPAD)
  int n = t / K, k = t % K;
  float v = (n < N) ? w[(size_t)k * N + n] : 0.f;
  wt[t] = __float2bfloat16(v);
  if (bp != nullptr && t < NPAD) bp[t] = (t < N) ? b[t] : 0.f;
}

// ---------------- combined off_w/aw_w -> Wt[256][768] bf16 + bias[256] f32 --------
__global__ __launch_bounds__(256) void prep_offaw_w_kernel(
    const float* __restrict__ ow, const float* __restrict__ aww,
    const float* __restrict__ ob, const float* __restrict__ awb,
    __hip_bfloat16* __restrict__ wt, float* __restrict__ bias)
{
  int t = blockIdx.x * 256 + threadIdx.x;   // n*768+k, n in [0,256)
  int n = t / kDIM, k = t % kDIM;
  float v = 0.f;
  if (n < 144)       v = ow[(size_t)k * 144 + n];
  else if (n < 216)  v = aww[(size_t)k * 72 + (n - 144)];
  wt[t] = __float2bfloat16(v);
  if (t < kOAW) {
    float b = 0.f;
    if (t < 144)       b = ob[t];
    else if (t < 216)  b = awb[t - 144];
    bias[t] = b;
  }
}

// ---------------- MFMA GEMM-BT: C[M][N] = A[M][KK] @ Bt[N][KK]^T ----------------
// A, Bt bf16 row-major. 128x128 tile, BK=64, 256 thr = 4 waves, 4x4 16x16x32 MFMA per wave.
// Grid: blockIdx.x = N-tile (inner, so consecutive blocks share the A-tile via L2),
//       blockIdx.y = M-tile.
// Staging: global_load_lds (16B/lane, linear LDS dest). The XOR swizzle lives on the
// per-lane GLOBAL source: lane l (wave w, iter i) loads row m = i*32+w*8+(l>>3),
// k-chunk (l&7)^(m&7), landing at LDS slot (m, l&7). Fragment reads use the same
// involution: slot (m, kc^(m&7)) holds global chunk kc.  [rule #21: both-sides]
// EPI 0: outB = bf16(acc + bias)                    (feat v-projection, ldc=768)
// EPI 1: outF = acc + bias + bf16 qln + f32 query   (op-projection + residuals, ldc=768)
// EPI 2: outF = acc + bias                          (off/aw logits & fc1, ldc=256)
// EPI 3: outF = acc + bias + query                  (fc2 + residual x, ldc=768)
template <int EPI, int KK>
__global__ __launch_bounds__(256) void gemm_bt_kernel(
    const unsigned short* __restrict__ A, const unsigned short* __restrict__ Bt,
    const float* __restrict__ bias,
    __hip_bfloat16* __restrict__ outB,
    const __hip_bfloat16* __restrict__ qln, const float* __restrict__ query,
    float* __restrict__ outF)
{
  constexpr int K = KK;
  constexpr int LDC = (EPI == 2) ? kOAW : kDIM;
  __shared__ unsigned short sA[128 * 64];
  __shared__ unsigned short sB[128 * 64];
  int tid = threadIdx.x;
  int wave = tid >> 6, lane = tid & 63;
  int tm = blockIdx.y * 128, tn = blockIdx.x * 128;
  int wm = (wave & 1) * 64, wn = (wave >> 1) * 64;
  floatx4 acc[4][4] = {};

  int sm_ = lane >> 3;      // row-within-8 for staging
  int sc_ = lane & 7;       // k-chunk slot for staging

  for (int k0 = 0; k0 < K; k0 += 64) {
    __syncthreads();
#pragma unroll
    for (int i = 0; i < 4; ++i) {
      int base_m = i * 32 + wave * 8;          // wave-uniform
      int m = base_m + sm_;
      int csrc = sc_ ^ (m & 7);
      GLD_LDS16(A + (size_t)(tm + m) * K + k0 + csrc * 8,
                (char*)sA + base_m * 128);
      GLD_LDS16(Bt + (size_t)(tn + m) * K + k0 + csrc * 8,
                (char*)sB + base_m * 128);
    }
    __syncthreads();
#pragma unroll
    for (int s = 0; s < 2; ++s) {
      int kc = s * 4 + (lane >> 4);
      short8 af[4], bfr[4];
#pragma unroll
      for (int i = 0; i < 4; ++i) {
        int mm = wm + i * 16 + (lane & 15);
        af[i] = *(const short8*)((const char*)sA + mm * 128 + ((kc ^ (mm & 7)) * 16));
        int nn = wn + i * 16 + (lane & 15);
        bfr[i] = *(const short8*)((const char*)sB + nn * 128 + ((kc ^ (nn & 7)) * 16));
      }
#pragma unroll
      for (int i = 0; i < 4; ++i)
#pragma unroll
        for (int j = 0; j < 4; ++j)
          acc[i][j] = __builtin_amdgcn_mfma_f32_16x16x32_bf16(af[i], bfr[j], acc[i][j], 0, 0, 0);
    }
  }

  // C/D layout (m89/m91 verified): col = lane&15, row = (lane>>4)*4 + reg
  int r0 = (lane >> 4) * 4, cc = lane & 15;
#pragma unroll
  for (int i = 0; i < 4; ++i) {
    int rowb = tm + wm + i * 16 + r0;
#pragma unroll
    for (int j = 0; j < 4; ++j) {
      int col = tn + wn + j * 16 + cc;
      float bv = bias[col];
#pragma unroll
      for (int r = 0; r < 4; ++r) {
        size_t o = (size_t)(rowb + r) * LDC + col;
        float val = acc[i][j][r] + bv;
        if constexpr (EPI == 0) {
          outB[o] = __float2bfloat16(val);
        } else if constexpr (EPI == 1) {
          outF[o] = val + bf2f(qln[o]) + query[o];
        } else if constexpr (EPI == 2) {
          outF[o] = val;
        } else {
          outF[o] = val + query[o];
        }
      }
    }
  }
}

// -------- softmax over the 12 aw logits per (row, head), in place in raw buffer --------
__global__ __launch_bounds__(256) void aw_softmax_kernel(float* __restrict__ raw)
{
  int t = blockIdx.x * 256 + threadIdx.x;   // row*6+h
  int row = t / kHEADS, h = t % kHEADS;
  float* p = raw + (size_t)row * kOAW + 144 + h * 12;
  float v[12];
  float m = -1e30f;
#pragma unroll
  for (int j = 0; j < 12; ++j) { v[j] = p[j]; m = fmaxf(m, v[j]); }
  float den = 0.f;
#pragma unroll
  for (int j = 0; j < 12; ++j) { v[j] = expf(v[j] - m); den += v[j]; }
  float inv = 1.f / den;
#pragma unroll
  for (int j = 0; j < 12; ++j) p[j] = v[j] * inv;
}

// -------- K4: bilinear sampling + attention-weighted sum (bf16 out) --------
// One block per PAIR of (b,q). Threads 0..143 precompute the 2x72 (head,level,point)
// corner descriptors (element offset + folded weight valid*cw*wgt) into LDS; then the
// 192 threads split 2 x 96: per query, h = t>>4, c0 = (t&15)*8 — each thread owns 8
// channels via uintx4 (16B = 8 bf16) loads. off/aw live in the combined raw buffer:
// row stride kOAW, off at cols [0,144), softmaxed aw at cols [144,216).
__global__ __launch_bounds__(192) void sample_kernel(
    const float* __restrict__ offaw,
    const float* __restrict__ refp, const __hip_bfloat16* __restrict__ v,
    __hip_bfloat16* __restrict__ samp)
{
  __shared__ __align__(16) int   idx_s[2][72][4];
  __shared__ __align__(16) float w_s[2][72][4];
  int tid = threadIdx.x;
  int bq0 = blockIdx.x * 2;

  if (tid < 144) {
    int q = (tid >= 72) ? 1 : 0;
    int t = tid - q * 72;
    int bq = bq0 + q;
    const int LH[3] = {128, 64, 32};
    const int LST[3] = {0, 16384, 20480};
    int h2 = t / 12, j = t % 12, l = j >> 2, p = j & 3;
    int Wl = LH[l];
    const float* base = offaw + (size_t)bq * kOAW;
    float rx = refp[(size_t)bq * 6 + l * 2 + 0];
    float ry = refp[(size_t)bq * 6 + l * 2 + 1];
    float ox = base[h2 * 24 + l * 8 + p * 2 + 0];
    float oy = base[h2 * 24 + l * 8 + p * 2 + 1];
    float wgt = base[144 + h2 * 12 + l * 4 + p];
    float xx = rx * Wl + ox - 0.5f;
    float yy = ry * Wl + oy - 0.5f;
    float x0f = floorf(xx), y0f = floorf(yy);
    int x0 = (int)x0f, y0 = (int)y0f;
    float wx = xx - x0f, wy = yy - y0f;
#pragma unroll
    for (int cy = 0; cy < 2; ++cy) {
#pragma unroll
      for (int cx = 0; cx < 2; ++cx) {
        int xi = x0 + cx, yi = y0 + cy;
        bool valid = (xi >= 0) && (xi < Wl) && (yi >= 0) && (yi < Wl);
        int xc = min(max(xi, 0), Wl - 1), yc = min(max(yi, 0), Wl - 1);
        float cw = (cx ? wx : 1.f - wx) * (cy ? wy : 1.f - wy);
        idx_s[q][t][cy * 2 + cx] = (LST[l] + yc * Wl + xc) * kDIM;
        w_s[q][t][cy * 2 + cx] = valid ? cw * wgt : 0.f;
      }
    }
  }
  __syncthreads();

  int q = (tid >= 96) ? 1 : 0;
  int t = tid - q * 96;
  int bq = bq0 + q;
  int b = bq >> 12;
  int h = t >> 4, c0 = (t & 15) * 8;
  const __hip_bfloat16* vb = v + (size_t)b * kNV * kDIM + h * kDH + c0;
  float a[8] = {};
#pragma unroll
  for (int j = 0; j < 12; ++j) {
    int tt = h * 12 + j;
    int4 ii = *(const int4*)idx_s[q][tt];
    float4 ww = *(const float4*)w_s[q][tt];
#pragma unroll
    for (int k = 0; k < 4; ++k) {
      int idx = (k == 0) ? ii.x : (k == 1) ? ii.y : (k == 2) ? ii.z : ii.w;
      float wv = (k == 0) ? ww.x : (k == 1) ? ww.y : (k == 2) ? ww.z : ww.w;
      uintx4 uv = *(const uintx4*)(vb + idx);
      a[0] += wv * bflo2f(uv.x); a[1] += wv * bfhi2f(uv.x);
      a[2] += wv * bflo2f(uv.y); a[3] += wv * bfhi2f(uv.y);
      a[4] += wv * bflo2f(uv.z); a[5] += wv * bfhi2f(uv.z);
      a[6] += wv * bflo2f(uv.w); a[7] += wv * bfhi2f(uv.w);
    }
  }
  uintx4 ov;
  ov.x = (unsigned)f2bfu(a[0]) | ((unsigned)f2bfu(a[1]) << 16);
  ov.y = (unsigned)f2bfu(a[2]) | ((unsigned)f2bfu(a[3]) << 16);
  ov.z = (unsigned)f2bfu(a[4]) | ((unsigned)f2bfu(a[5]) << 16);
  ov.w = (unsigned)f2bfu(a[6]) | ((unsigned)f2bfu(a[7]) << 16);
  *(uintx4*)(samp + (size_t)bq * kDIM + h * kDH + c0) = ov;
}

// -------- K7: y2 = bf16(gelu(dwconv3x3(y1p) + dw_b)), y1p has row stride 256 --------
__global__ __launch_bounds__(256) void dwconv_gelu_kernel(
    const float* __restrict__ y1, const float* __restrict__ w,
    const float* __restrict__ bias, __hip_bfloat16* __restrict__ y2)
{
  int idx = blockIdx.x * 256 + threadIdx.x;
  int c = idx % kHID;
  int sp = idx / kHID;
  int j = sp % kW0;
  int i = (sp / kW0) % kH0;
  int b = sp / (kW0 * kH0);
  float s = bias[c];
#pragma unroll
  for (int ky = 0; ky < 3; ++ky) {
    int yi = i + ky - 1;
    if (yi < 0 || yi >= kH0) continue;
#pragma unroll
    for (int kx = 0; kx < 3; ++kx) {
      int xj = j + kx - 1;
      if (xj < 0 || xj >= kW0) continue;
      s += y1[(((size_t)b * kH0 + yi) * kW0 + xj) * kOAW + c] * w[(ky * 3 + kx) * kHID + c];
    }
  }
  float gl = 0.5f * s * (1.f + erff(s * 0.70710678118654752440f));
  y2[idx] = __float2bfloat16(gl);
}

extern "C" void kernel_launch(void* const* d_in, const int* in_sizes, int n_in,
                              void* d_out, int out_size, void* d_ws, size_t ws_size,
                              hipStream_t stream)
{
  const float* query = (const float*)d_in[0];
  const float* refp  = (const float*)d_in[1];
  const float* feat  = (const float*)d_in[2];
  const float* qn_g  = (const float*)d_in[7];
  const float* qn_b  = (const float*)d_in[8];
  const float* fn_g  = (const float*)d_in[9];
  const float* fn_b  = (const float*)d_in[10];
  const float* off_w = (const float*)d_in[11];
  const float* off_b = (const float*)d_in[12];
  const float* aw_w  = (const float*)d_in[13];
  const float* aw_b  = (const float*)d_in[14];
  const float* vp_w  = (const float*)d_in[15];
  const float* vp_b  = (const float*)d_in[16];
  const float* op_w  = (const float*)d_in[17];
  const float* op_b  = (const float*)d_in[18];
  const float* ffn_g = (const float*)d_in[19];
  const float* ffn_b = (const float*)d_in[20];
  const float* fc1_w = (const float*)d_in[21];
  const float* fc1_b = (const float*)d_in[22];
  const float* dw_w  = (const float*)d_in[23];
  const float* dw_b  = (const float*)d_in[24];
  const float* fc2_w = (const float*)d_in[25];
  const float* fc2_b = (const float*)d_in[26];

  char* ws = (char*)d_ws;
  // workspace (total 218,400,768 B; known-safe budget 221,773,824):
  // R0 @ 0 (66,060,288), time-multiplexed:
  //   phase A: a_ln bf16 chunk (43008x768)            [ln_feat -> gemm, per chunk]
  //   phase B: q_ln bf16 @0 (25,165,824)              [ln_q -> offaw gemm + opproj epi]
  //            samp bf16 @39,321,600 (25,165,824)     [sample -> opproj]
  //   phase C (after opproj): x_ln bf16 @0 (25,165,824)      [ln_ffn -> fc1 gemm]
  //            y1p f32 @25,165,824 (16,777,216, ldc 256)     [fc1 -> dwconv]
  //            y2 bf16 @41,943,040 (6,291,456)               [dwconv -> fc2]
  // V  @ 66,060,288 (132,120,576):
  //   phase A/B: v bf16 (86016x768)                   [gemm -> sample]
  //   phase C: x f32 @66,060,288 (50,331,648)         [opproj -> fc2 residual]
  // W  @ 198,180,864: vp_w_t bf16 (1,179,648) ; op_w_t bf16 @199,360,512 (1,179,648)
  // OA @ 200,540,160: offaw raw f32 (16384x256 = 16,777,216)
  //    @ 217,317,376: offaw_wt bf16 (393,216)
  //    @ 217,710,592: offaw_bias f32 (1,024)
  // FFN @ 217,711,616: fc1_wt bf16 [256][768] (393,216)
  //     @ 218,104,832: fc1_bp f32 [256] (1,024)
  //     @ 218,105,856: fc2_wt bf16 [768][192] (294,912) -> ends 218,400,768
  constexpr size_t kWsNeeded = 218400768ull;
  if (ws_size < kWsNeeded) return;

  __hip_bfloat16* a_ln     = (__hip_bfloat16*)(ws + 0);
  __hip_bfloat16* q_ln     = (__hip_bfloat16*)(ws + 0);
  __hip_bfloat16* x_ln     = (__hip_bfloat16*)(ws + 0);
  float*          y1p      = (float*)(ws + 25165824ull);
  __hip_bfloat16* samp     = (__hip_bfloat16*)(ws + 39321600ull);
  __hip_bfloat16* y2       = (__hip_bfloat16*)(ws + 41943040ull);
  __hip_bfloat16* v        = (__hip_bfloat16*)(ws + 66060288ull);
  float*          x        = (float*)(ws + 66060288ull);
  __hip_bfloat16* vp_w_t   = (__hip_bfloat16*)(ws + 198180864ull);
  __hip_bfloat16* op_w_t   = (__hip_bfloat16*)(ws + 199360512ull);
  float*          oa_raw   = (float*)(ws + 200540160ull);
  __hip_bfloat16* oa_wt    = (__hip_bfloat16*)(ws + 217317376ull);
  float*          oa_bias  = (float*)(ws + 217710592ull);
  __hip_bfloat16* fc1_wt   = (__hip_bfloat16*)(ws + 217711616ull);
  float*          fc1_bp   = (float*)(ws + 218104832ull);
  __hip_bfloat16* fc2_wt   = (__hip_bfloat16*)(ws + 218105856ull);

  constexpr int NROWQ = kB * kNQ;          // 16384
  constexpr int NROWV = kB * kNV;          // 86016
  constexpr int CHUNK = NROWV / 2;         // 43008

  // weight prep
  transpose_w_kernel<<<(kDIM * kDIM) / 256, 256, 0, stream>>>(vp_w, vp_w_t);
  transpose_w_kernel<<<(kDIM * kDIM) / 256, 256, 0, stream>>>(op_w, op_w_t);
  prep_offaw_w_kernel<<<(kOAW * kDIM) / 256, 256, 0, stream>>>(
      off_w, aw_w, off_b, aw_b, oa_wt, oa_bias);
  prep_wt_kernel<768, 192, 256><<<(256 * 768) / 256, 256, 0, stream>>>(
      fc1_w, fc1_b, fc1_wt, fc1_bp);
  prep_wt_kernel<192, 768, 768><<<(768 * 192) / 256, 256, 0, stream>>>(
      fc2_w, nullptr, fc2_wt, nullptr);

  // phase A: v = LN(feat) @ vp_w + vp_b, two M-chunks through the shared a_ln buffer
  for (int c = 0; c < 2; ++c) {
    ln_bf16_kernel<<<CHUNK / 8, 256, 0, stream>>>(
        feat + (size_t)c * CHUNK * kDIM, fn_g, fn_b, a_ln);
    gemm_bt_kernel<0, kDIM><<<dim3(kDIM / 128, CHUNK / 128), 256, 0, stream>>>(
        (const unsigned short*)a_ln, (const unsigned short*)vp_w_t, vp_b,
        v + (size_t)c * CHUNK * kDIM, nullptr, nullptr, nullptr);
  }

  // phase B
  ln_bf16_kernel<<<NROWQ / 8, 256, 0, stream>>>(query, qn_g, qn_b, q_ln);
  gemm_bt_kernel<2, kDIM><<<dim3(kOAW / 128, NROWQ / 128), 256, 0, stream>>>(
      (const unsigned short*)q_ln, (const unsigned short*)oa_wt, oa_bias,
      nullptr, nullptr, nullptr, oa_raw);
  aw_softmax_kernel<<<(NROWQ * kHEADS) / 256, 256, 0, stream>>>(oa_raw);
  sample_kernel<<<NROWQ / 2, 192, 0, stream>>>(oa_raw, refp, v, samp);
  gemm_bt_kernel<1, kDIM><<<dim3(kDIM / 128, NROWQ / 128), 256, 0, stream>>>(
      (const unsigned short*)samp, (const unsigned short*)op_w_t, op_b,
      nullptr, q_ln, query, x);

  // phase C: FFN, all matmuls via MFMA
  ln_bf16_kernel<<<NROWQ / 8, 256, 0, stream>>>(x, ffn_g, ffn_b, x_ln);
  gemm_bt_kernel<2, kDIM><<<dim3(kOAW / 128, NROWQ / 128), 256, 0, stream>>>(
      (const unsigned short*)x_ln, (const unsigned short*)fc1_wt, fc1_bp,
      nullptr, nullptr, nullptr, y1p);
  dwconv_gelu_kernel<<<(NROWQ * kHID) / 256, 256, 0, stream>>>(y1p, dw_w, dw_b, y2);
  gemm_bt_kernel<3, kHID><<<dim3(kDIM / 128, NROWQ / 128), 256, 0, stream>>>(
      (const unsigned short*)y2, (const unsigned short*)fc2_wt, fc2_b,
      nullptr, nullptr, x, (float*)d_out);
}

// Round 4
// 835.147 us; speedup vs baseline: 1.9914x; 1.0414x over previous
//
#include <hip/hip_runtime.h>
#include <hip/hip_bf16.h>

constexpr int kDIM = 768;
constexpr int kHEADS = 6;
constexpr int kLEVELS = 3;
constexpr int kPOINTS = 4;
constexpr int kHID = 192;
constexpr int kB = 4;
constexpr int kH0 = 64;
constexpr int kW0 = 64;
constexpr int kNQ = kH0 * kW0;   // 4096
constexpr int kNV = 21504;       // 128*128 + 64*64 + 32*32
constexpr int kDH = 128;         // head dim
constexpr float kEPS = 1e-6f;
constexpr int kOAW = 256;        // padded off+aw / fc1 output columns

typedef __attribute__((ext_vector_type(8))) short short8;     // 8 bf16 = 4 VGPRs (MFMA A/B frag)
typedef __attribute__((ext_vector_type(4))) float floatx4;    // MFMA C/D frag
typedef __attribute__((ext_vector_type(4))) unsigned int uintx4;

__device__ __forceinline__ float bf2f(__hip_bfloat16 x) { return __bfloat162float(x); }
__device__ __forceinline__ float bflo2f(unsigned int u) { return __uint_as_float(u << 16); }
__device__ __forceinline__ float bfhi2f(unsigned int u) { return __uint_as_float(u & 0xffff0000u); }
__device__ __forceinline__ unsigned short f2bfu(float f) {
  __hip_bfloat16 h = __float2bfloat16(f);
  return *reinterpret_cast<unsigned short*>(&h);
}

#define GLD_LDS16(g, l) \
  __builtin_amdgcn_global_load_lds( \
      (const __attribute__((address_space(1))) void*)(g), \
      (__attribute__((address_space(3))) void*)(l), 16, 0, 0)

// ---------------- LN -> bf16 out (query, feat chunks, ffn-LN of x) ----------------
// float4 loads (16 B/lane), ushort4 stores (8 B/lane)  [G13]
__global__ __launch_bounds__(256) void ln_bf16_kernel(
    const float* __restrict__ x, const float* __restrict__ g,
    const float* __restrict__ b, __hip_bfloat16* __restrict__ out)
{
  constexpr int MT = 8;
  constexpr int NV4 = kDIM / 4 / 32;   // 6 float4 per lane
  int tid = threadIdx.x, grp = tid >> 5, lane = tid & 31;
  size_t row = (size_t)blockIdx.x * MT + grp;
  const float4* xr = (const float4*)(x + row * kDIM);
  float4 buf[NV4];
  float s = 0.f;
#pragma unroll
  for (int i = 0; i < NV4; ++i) {
    float4 v = xr[lane + i * 32];
    buf[i] = v;
    s += v.x + v.y + v.z + v.w;
  }
  for (int d = 16; d > 0; d >>= 1) s += __shfl_down(s, d, 32);
  float mean = __shfl(s, 0, 32) * (1.f / kDIM);
  float vs = 0.f;
#pragma unroll
  for (int i = 0; i < NV4; ++i) {
    float4 v = buf[i];
    float d0 = v.x - mean, d1 = v.y - mean, d2 = v.z - mean, d3 = v.w - mean;
    vs += d0 * d0 + d1 * d1 + d2 * d2 + d3 * d3;
  }
  for (int d = 16; d > 0; d >>= 1) vs += __shfl_down(vs, d, 32);
  float rstd = rsqrtf(__shfl(vs, 0, 32) * (1.f / kDIM) + kEPS);
  const float4* gg = (const float4*)g;
  const float4* bb = (const float4*)b;
  ushort4* orow = (ushort4*)(out + row * kDIM);
#pragma unroll
  for (int i = 0; i < NV4; ++i) {
    int k = lane + i * 32;
    float4 gv = gg[k], bv = bb[k], v = buf[i];
    ushort4 o;
    o.x = f2bfu((v.x - mean) * rstd * gv.x + bv.x);
    o.y = f2bfu((v.y - mean) * rstd * gv.y + bv.y);
    o.z = f2bfu((v.z - mean) * rstd * gv.z + bv.z);
    o.w = f2bfu((v.w - mean) * rstd * gv.w + bv.w);
    orow[k] = o;
  }
}

// ---------------- W[k][n] f32 -> Wt[n][k] bf16 (768x768) ----------------
__global__ __launch_bounds__(256) void transpose_w_kernel(
    const float* __restrict__ w, __hip_bfloat16* __restrict__ wt)
{
  int t = blockIdx.x * 256 + threadIdx.x;   // n*768+k
  int n = t / kDIM, k = t % kDIM;
  wt[t] = __float2bfloat16(w[(size_t)k * kDIM + n]);
}

// ------- generic W[K][N] f32 -> Wt[NPAD][K] bf16 (rows >= N zero) + bias pad -------
template <int K, int N, int NPAD>
__global__ __launch_bounds__(256) void prep_wt_kernel(
    const float* __restrict__ w, const float* __restrict__ b,
    __hip_bfloat16* __restrict__ wt, float* __restrict__ bp)
{
  int t = blockIdx.x * 256 + threadIdx.x;   // n*K + k, n in [0, NPAD)
  int n = t / K, k = t % K;
  float v = (n < N) ? w[(size_t)k * N + n] : 0.f;
  wt[t] = __float2bfloat16(v);
  if (bp != nullptr && t < NPAD) bp[t] = (t < N) ? b[t] : 0.f;
}

// ---------------- combined off_w/aw_w -> Wt[256][768] bf16 + bias[256] f32 --------
__global__ __launch_bounds__(256) void prep_offaw_w_kernel(
    const float* __restrict__ ow, const float* __restrict__ aww,
    const float* __restrict__ ob, const float* __restrict__ awb,
    __hip_bfloat16* __restrict__ wt, float* __restrict__ bias)
{
  int t = blockIdx.x * 256 + threadIdx.x;   // n*768+k, n in [0,256)
  int n = t / kDIM, k = t % kDIM;
  float v = 0.f;
  if (n < 144)       v = ow[(size_t)k * 144 + n];
  else if (n < 216)  v = aww[(size_t)k * 72 + (n - 144)];
  wt[t] = __float2bfloat16(v);
  if (t < kOAW) {
    float b = 0.f;
    if (t < 144)       b = ob[t];
    else if (t < 216)  b = awb[t - 144];
    bias[t] = b;
  }
}

// ======== 256x256 phase-split GEMM-BT for the v-projection (K=768, EPI 0) ========
// C[M][768] = bf16(A[M][768] @ Bt[768][768]^T + bias). 512 thr = 8 waves (2M x 4N),
// per-wave output 128x64 (8x4 16x16 frags), BK=64, double-buffered LDS (128 KiB).
// Stage-ahead-by-one: all 8 global_load_lds for tile t+1 are issued BEFORE tile t's
// compute phases, so the boundary __syncthreads' vmcnt(0) drain is latency-covered.
// Fragments are read ONCE per K-tile (LDS-traffic minimum), split in 2 kk-phases
// with s_barrier + setprio(1) around each 32-MFMA cluster (T3/T5).
// XOR swizzle both-sides [rule #21]: LDS slot (m,s) holds global chunk s^(m&7).
// XCD-bijective block swizzle (grid % 8 == 0 required).
__global__ __launch_bounds__(512, 2) void gemm256_bt_kernel(
    const unsigned short* __restrict__ A, const unsigned short* __restrict__ Bt,
    const float* __restrict__ bias, __hip_bfloat16* __restrict__ outB, int nx)
{
  constexpr int K = kDIM;           // 768 -> 12 K-tiles
  __shared__ unsigned short sA[2][256 * 64];
  __shared__ unsigned short sB[2][256 * 64];
  int tid = threadIdx.x;
  int wave = tid >> 6, lane = tid & 63;

  int cpx = gridDim.x >> 3;
  int orig = blockIdx.x;
  int swz = (orig & 7) * cpx + (orig >> 3);   // same-XCD blocks get consecutive tiles
  int tn = (swz % nx) * 256;
  int tm = (swz / nx) * 256;

  int wmb = (wave >> 2) * 128;      // 0 / 128
  int wnb = (wave & 3) * 64;        // 0,64,128,192
  floatx4 acc[8][4] = {};
  int sr = lane >> 3, sc = lane & 7;

  auto stage = [&](unsigned short* dA, unsigned short* dB, int k0) {
#pragma unroll
    for (int i = 0; i < 4; ++i) {
      int base = i * 64 + wave * 8;        // wave-uniform row base
      int m = base + sr;
      int cs = sc ^ (m & 7);
      GLD_LDS16(A + (size_t)(tm + m) * K + k0 + cs * 8, (char*)dA + base * 128);
      GLD_LDS16(Bt + (size_t)(tn + m) * K + k0 + cs * 8, (char*)dB + base * 128);
    }
  };

  stage(sA[0], sB[0], 0);
  __syncthreads();

  for (int t = 0; t < K / 64; ++t) {
    int cur = t & 1;
    if (t < K / 64 - 1) stage(sA[cur ^ 1], sB[cur ^ 1], (t + 1) * 64);
    const char* pA = (const char*)sA[cur];
    const char* pB = (const char*)sB[cur];
#pragma unroll
    for (int kk = 0; kk < 2; ++kk) {
      int kc = kk * 4 + (lane >> 4);
      short8 af[8], bfr[4];
#pragma unroll
      for (int i = 0; i < 8; ++i) {
        int mm = wmb + i * 16 + (lane & 15);
        af[i] = *(const short8*)(pA + mm * 128 + ((kc ^ (mm & 7)) * 16));
      }
#pragma unroll
      for (int j = 0; j < 4; ++j) {
        int nn = wnb + j * 16 + (lane & 15);
        bfr[j] = *(const short8*)(pB + nn * 128 + ((kc ^ (nn & 7)) * 16));
      }
      __builtin_amdgcn_s_setprio(1);
#pragma unroll
      for (int i = 0; i < 8; ++i)
#pragma unroll
        for (int j = 0; j < 4; ++j)
          acc[i][j] = __builtin_amdgcn_mfma_f32_16x16x32_bf16(af[i], bfr[j], acc[i][j], 0, 0, 0);
      __builtin_amdgcn_s_setprio(0);
      if (kk == 0) __builtin_amdgcn_s_barrier();
    }
    __syncthreads();    // vmcnt(0)+lgkmcnt(0)+barrier: t+1 staged, buf[cur] reads done
  }

  // C/D layout: col = lane&15, row = (lane>>4)*4 + reg
  int r0 = (lane >> 4) * 4, cc = lane & 15;
#pragma unroll
  for (int i = 0; i < 8; ++i) {
    int rowb = tm + wmb + i * 16 + r0;
#pragma unroll
    for (int j = 0; j < 4; ++j) {
      int col = tn + wnb + j * 16 + cc;
      float bv = bias[col];
#pragma unroll
      for (int r = 0; r < 4; ++r)
        outB[(size_t)(rowb + r) * kDIM + col] = __float2bfloat16(acc[i][j][r] + bv);
    }
  }
}

// ---------------- MFMA GEMM-BT: C[M][N] = A[M][KK] @ Bt[N][KK]^T ----------------
// A, Bt bf16 row-major. 128x128 tile, BK=64, 256 thr = 4 waves, 4x4 16x16x32 MFMA per wave.
// Grid: blockIdx.x = N-tile (inner), blockIdx.y = M-tile.
// Staging: global_load_lds, linear LDS dest, XOR swizzle on the per-lane GLOBAL source.
// EPI 1: outF = acc + bias + bf16 qln + f32 query   (op-projection + residuals, ldc=768)
// EPI 2: outF = acc + bias                          (off/aw logits & fc1, ldc=256)
// EPI 3: outF = acc + bias + query                  (fc2 + residual x, ldc=768)
template <int EPI, int KK>
__global__ __launch_bounds__(256) void gemm_bt_kernel(
    const unsigned short* __restrict__ A, const unsigned short* __restrict__ Bt,
    const float* __restrict__ bias,
    __hip_bfloat16* __restrict__ outB,
    const __hip_bfloat16* __restrict__ qln, const float* __restrict__ query,
    float* __restrict__ outF)
{
  constexpr int K = KK;
  constexpr int LDC = (EPI == 2) ? kOAW : kDIM;
  __shared__ unsigned short sA[128 * 64];
  __shared__ unsigned short sB[128 * 64];
  int tid = threadIdx.x;
  int wave = tid >> 6, lane = tid & 63;
  int tm = blockIdx.y * 128, tn = blockIdx.x * 128;
  int wm = (wave & 1) * 64, wn = (wave >> 1) * 64;
  floatx4 acc[4][4] = {};

  int sm_ = lane >> 3;      // row-within-8 for staging
  int sc_ = lane & 7;       // k-chunk slot for staging

  for (int k0 = 0; k0 < K; k0 += 64) {
    __syncthreads();
#pragma unroll
    for (int i = 0; i < 4; ++i) {
      int base_m = i * 32 + wave * 8;          // wave-uniform
      int m = base_m + sm_;
      int csrc = sc_ ^ (m & 7);
      GLD_LDS16(A + (size_t)(tm + m) * K + k0 + csrc * 8,
                (char*)sA + base_m * 128);
      GLD_LDS16(Bt + (size_t)(tn + m) * K + k0 + csrc * 8,
                (char*)sB + base_m * 128);
    }
    __syncthreads();
#pragma unroll
    for (int s = 0; s < 2; ++s) {
      int kc = s * 4 + (lane >> 4);
      short8 af[4], bfr[4];
#pragma unroll
      for (int i = 0; i < 4; ++i) {
        int mm = wm + i * 16 + (lane & 15);
        af[i] = *(const short8*)((const char*)sA + mm * 128 + ((kc ^ (mm & 7)) * 16));
        int nn = wn + i * 16 + (lane & 15);
        bfr[i] = *(const short8*)((const char*)sB + nn * 128 + ((kc ^ (nn & 7)) * 16));
      }
#pragma unroll
      for (int i = 0; i < 4; ++i)
#pragma unroll
        for (int j = 0; j < 4; ++j)
          acc[i][j] = __builtin_amdgcn_mfma_f32_16x16x32_bf16(af[i], bfr[j], acc[i][j], 0, 0, 0);
    }
  }

  // C/D layout (m89/m91 verified): col = lane&15, row = (lane>>4)*4 + reg
  int r0 = (lane >> 4) * 4, cc = lane & 15;
#pragma unroll
  for (int i = 0; i < 4; ++i) {
    int rowb = tm + wm + i * 16 + r0;
#pragma unroll
    for (int j = 0; j < 4; ++j) {
      int col = tn + wn + j * 16 + cc;
      float bv = bias[col];
#pragma unroll
      for (int r = 0; r < 4; ++r) {
        size_t o = (size_t)(rowb + r) * LDC + col;
        float val = acc[i][j][r] + bv;
        if constexpr (EPI == 1) {
          outF[o] = val + bf2f(qln[o]) + query[o];
        } else if constexpr (EPI == 2) {
          outF[o] = val;
        } else {
          outF[o] = val + query[o];
        }
      }
    }
  }
}

// -------- softmax over the 12 aw logits per (row, head), in place in raw buffer --------
__global__ __launch_bounds__(256) void aw_softmax_kernel(float* __restrict__ raw)
{
  int t = blockIdx.x * 256 + threadIdx.x;   // row*6+h
  int row = t / kHEADS, h = t % kHEADS;
  float* p = raw + (size_t)row * kOAW + 144 + h * 12;
  float v[12];
  float m = -1e30f;
#pragma unroll
  for (int j = 0; j < 12; ++j) { v[j] = p[j]; m = fmaxf(m, v[j]); }
  float den = 0.f;
#pragma unroll
  for (int j = 0; j < 12; ++j) { v[j] = expf(v[j] - m); den += v[j]; }
  float inv = 1.f / den;
#pragma unroll
  for (int j = 0; j < 12; ++j) p[j] = v[j] * inv;
}

// -------- K4: bilinear sampling + attention-weighted sum (bf16 out) --------
// One block per PAIR of (b,q). Threads 0..143 precompute the 2x72 (head,level,point)
// corner descriptors (element offset + folded weight valid*cw*wgt) into LDS; then the
// 192 threads split 2 x 96: per query, h = t>>4, c0 = (t&15)*8 — each thread owns 8
// channels via uintx4 (16B = 8 bf16) loads. off/aw live in the combined raw buffer:
// row stride kOAW, off at cols [0,144), softmaxed aw at cols [144,216).
__global__ __launch_bounds__(192) void sample_kernel(
    const float* __restrict__ offaw,
    const float* __restrict__ refp, const __hip_bfloat16* __restrict__ v,
    __hip_bfloat16* __restrict__ samp)
{
  __shared__ __align__(16) int   idx_s[2][72][4];
  __shared__ __align__(16) float w_s[2][72][4];
  int tid = threadIdx.x;
  int bq0 = blockIdx.x * 2;

  if (tid < 144) {
    int q = (tid >= 72) ? 1 : 0;
    int t = tid - q * 72;
    int bq = bq0 + q;
    const int LH[3] = {128, 64, 32};
    const int LST[3] = {0, 16384, 20480};
    int h2 = t / 12, j = t % 12, l = j >> 2, p = j & 3;
    int Wl = LH[l];
    const float* base = offaw + (size_t)bq * kOAW;
    float rx = refp[(size_t)bq * 6 + l * 2 + 0];
    float ry = refp[(size_t)bq * 6 + l * 2 + 1];
    float ox = base[h2 * 24 + l * 8 + p * 2 + 0];
    float oy = base[h2 * 24 + l * 8 + p * 2 + 1];
    float wgt = base[144 + h2 * 12 + l * 4 + p];
    float xx = rx * Wl + ox - 0.5f;
    float yy = ry * Wl + oy - 0.5f;
    float x0f = floorf(xx), y0f = floorf(yy);
    int x0 = (int)x0f, y0 = (int)y0f;
    float wx = xx - x0f, wy = yy - y0f;
#pragma unroll
    for (int cy = 0; cy < 2; ++cy) {
#pragma unroll
      for (int cx = 0; cx < 2; ++cx) {
        int xi = x0 + cx, yi = y0 + cy;
        bool valid = (xi >= 0) && (xi < Wl) && (yi >= 0) && (yi < Wl);
        int xc = min(max(xi, 0), Wl - 1), yc = min(max(yi, 0), Wl - 1);
        float cw = (cx ? wx : 1.f - wx) * (cy ? wy : 1.f - wy);
        idx_s[q][t][cy * 2 + cx] = (LST[l] + yc * Wl + xc) * kDIM;
        w_s[q][t][cy * 2 + cx] = valid ? cw * wgt : 0.f;
      }
    }
  }
  __syncthreads();

  int q = (tid >= 96) ? 1 : 0;
  int t = tid - q * 96;
  int bq = bq0 + q;
  int b = bq >> 12;
  int h = t >> 4, c0 = (t & 15) * 8;
  const __hip_bfloat16* vb = v + (size_t)b * kNV * kDIM + h * kDH + c0;
  float a[8] = {};
#pragma unroll
  for (int j = 0; j < 12; ++j) {
    int tt = h * 12 + j;
    int4 ii = *(const int4*)idx_s[q][tt];
    float4 ww = *(const float4*)w_s[q][tt];
#pragma unroll
    for (int k = 0; k < 4; ++k) {
      int idx = (k == 0) ? ii.x : (k == 1) ? ii.y : (k == 2) ? ii.z : ii.w;
      float wv = (k == 0) ? ww.x : (k == 1) ? ww.y : (k == 2) ? ww.z : ww.w;
      uintx4 uv = *(const uintx4*)(vb + idx);
      a[0] += wv * bflo2f(uv.x); a[1] += wv * bfhi2f(uv.x);
      a[2] += wv * bflo2f(uv.y); a[3] += wv * bfhi2f(uv.y);
      a[4] += wv * bflo2f(uv.z); a[5] += wv * bfhi2f(uv.z);
      a[6] += wv * bflo2f(uv.w); a[7] += wv * bfhi2f(uv.w);
    }
  }
  uintx4 ov;
  ov.x = (unsigned)f2bfu(a[0]) | ((unsigned)f2bfu(a[1]) << 16);
  ov.y = (unsigned)f2bfu(a[2]) | ((unsigned)f2bfu(a[3]) << 16);
  ov.z = (unsigned)f2bfu(a[4]) | ((unsigned)f2bfu(a[5]) << 16);
  ov.w = (unsigned)f2bfu(a[6]) | ((unsigned)f2bfu(a[7]) << 16);
  *(uintx4*)(samp + (size_t)bq * kDIM + h * kDH + c0) = ov;
}

// -------- K7: y2 = bf16(gelu(dwconv3x3(y1p) + dw_b)), y1p has row stride 256 --------
__global__ __launch_bounds__(256) void dwconv_gelu_kernel(
    const float* __restrict__ y1, const float* __restrict__ w,
    const float* __restrict__ bias, __hip_bfloat16* __restrict__ y2)
{
  int idx = blockIdx.x * 256 + threadIdx.x;
  int c = idx % kHID;
  int sp = idx / kHID;
  int j = sp % kW0;
  int i = (sp / kW0) % kH0;
  int b = sp / (kW0 * kH0);
  float s = bias[c];
#pragma unroll
  for (int ky = 0; ky < 3; ++ky) {
    int yi = i + ky - 1;
    if (yi < 0 || yi >= kH0) continue;
#pragma unroll
    for (int kx = 0; kx < 3; ++kx) {
      int xj = j + kx - 1;
      if (xj < 0 || xj >= kW0) continue;
      s += y1[(((size_t)b * kH0 + yi) * kW0 + xj) * kOAW + c] * w[(ky * 3 + kx) * kHID + c];
    }
  }
  float gl = 0.5f * s * (1.f + erff(s * 0.70710678118654752440f));
  y2[idx] = __float2bfloat16(gl);
}

extern "C" void kernel_launch(void* const* d_in, const int* in_sizes, int n_in,
                              void* d_out, int out_size, void* d_ws, size_t ws_size,
                              hipStream_t stream)
{
  const float* query = (const float*)d_in[0];
  const float* refp  = (const float*)d_in[1];
  const float* feat  = (const float*)d_in[2];
  const float* qn_g  = (const float*)d_in[7];
  const float* qn_b  = (const float*)d_in[8];
  const float* fn_g  = (const float*)d_in[9];
  const float* fn_b  = (const float*)d_in[10];
  const float* off_w = (const float*)d_in[11];
  const float* off_b = (const float*)d_in[12];
  const float* aw_w  = (const float*)d_in[13];
  const float* aw_b  = (const float*)d_in[14];
  const float* vp_w  = (const float*)d_in[15];
  const float* vp_b  = (const float*)d_in[16];
  const float* op_w  = (const float*)d_in[17];
  const float* op_b  = (const float*)d_in[18];
  const float* ffn_g = (const float*)d_in[19];
  const float* ffn_b = (const float*)d_in[20];
  const float* fc1_w = (const float*)d_in[21];
  const float* fc1_b = (const float*)d_in[22];
  const float* dw_w  = (const float*)d_in[23];
  const float* dw_b  = (const float*)d_in[24];
  const float* fc2_w = (const float*)d_in[25];
  const float* fc2_b = (const float*)d_in[26];

  char* ws = (char*)d_ws;
  // workspace layout unchanged (total 218,400,768 B; known-safe budget 221,773,824):
  // R0 @ 0 (66,060,288), time-multiplexed:
  //   phase A: a_ln bf16 chunk (43008x768)            [ln_feat -> gemm256, per chunk]
  //   phase B: q_ln bf16 @0 (25,165,824)              [ln_q -> offaw gemm + opproj epi]
  //            samp bf16 @39,321,600 (25,165,824)     [sample -> opproj]
  //   phase C (after opproj): x_ln bf16 @0 (25,165,824)      [ln_ffn -> fc1 gemm]
  //            y1p f32 @25,165,824 (16,777,216, ldc 256)     [fc1 -> dwconv]
  //            y2 bf16 @41,943,040 (6,291,456)               [dwconv -> fc2]
  // V  @ 66,060,288 (132,120,576):
  //   phase A/B: v bf16 (86016x768)                   [gemm256 -> sample]
  //   phase C: x f32 @66,060,288 (50,331,648)         [opproj -> fc2 residual]
  // W  @ 198,180,864: vp_w_t bf16 (1,179,648) ; op_w_t bf16 @199,360,512 (1,179,648)
  // OA @ 200,540,160: offaw raw f32 (16384x256 = 16,777,216)
  //    @ 217,317,376: offaw_wt bf16 (393,216)
  //    @ 217,710,592: offaw_bias f32 (1,024)
  // FFN @ 217,711,616: fc1_wt bf16 [256][768] (393,216)
  //     @ 218,104,832: fc1_bp f32 [256] (1,024)
  //     @ 218,105,856: fc2_wt bf16 [768][192] (294,912) -> ends 218,400,768
  constexpr size_t kWsNeeded = 218400768ull;
  if (ws_size < kWsNeeded) return;

  __hip_bfloat16* a_ln     = (__hip_bfloat16*)(ws + 0);
  __hip_bfloat16* q_ln     = (__hip_bfloat16*)(ws + 0);
  __hip_bfloat16* x_ln     = (__hip_bfloat16*)(ws + 0);
  float*          y1p      = (float*)(ws + 25165824ull);
  __hip_bfloat16* samp     = (__hip_bfloat16*)(ws + 39321600ull);
  __hip_bfloat16* y2       = (__hip_bfloat16*)(ws + 41943040ull);
  __hip_bfloat16* v        = (__hip_bfloat16*)(ws + 66060288ull);
  float*          x        = (float*)(ws + 66060288ull);
  __hip_bfloat16* vp_w_t   = (__hip_bfloat16*)(ws + 198180864ull);
  __hip_bfloat16* op_w_t   = (__hip_bfloat16*)(ws + 199360512ull);
  float*          oa_raw   = (float*)(ws + 200540160ull);
  __hip_bfloat16* oa_wt    = (__hip_bfloat16*)(ws + 217317376ull);
  float*          oa_bias  = (float*)(ws + 217710592ull);
  __hip_bfloat16* fc1_wt   = (__hip_bfloat16*)(ws + 217711616ull);
  float*          fc1_bp   = (float*)(ws + 218104832ull);
  __hip_bfloat16* fc2_wt   = (__hip_bfloat16*)(ws + 218105856ull);

  constexpr int NROWQ = kB * kNQ;          // 16384
  constexpr int NROWV = kB * kNV;          // 86016
  constexpr int CHUNK = NROWV / 2;         // 43008

  // weight prep
  transpose_w_kernel<<<(kDIM * kDIM) / 256, 256, 0, stream>>>(vp_w, vp_w_t);
  transpose_w_kernel<<<(kDIM * kDIM) / 256, 256, 0, stream>>>(op_w, op_w_t);
  prep_offaw_w_kernel<<<(kOAW * kDIM) / 256, 256, 0, stream>>>(
      off_w, aw_w, off_b, aw_b, oa_wt, oa_bias);
  prep_wt_kernel<768, 192, 256><<<(256 * 768) / 256, 256, 0, stream>>>(
      fc1_w, fc1_b, fc1_wt, fc1_bp);
  prep_wt_kernel<192, 768, 768><<<(768 * 192) / 256, 256, 0, stream>>>(
      fc2_w, nullptr, fc2_wt, nullptr);

  // phase A: v = LN(feat) @ vp_w + vp_b, two M-chunks through the shared a_ln buffer
  for (int c = 0; c < 2; ++c) {
    ln_bf16_kernel<<<CHUNK / 8, 256, 0, stream>>>(
        feat + (size_t)c * CHUNK * kDIM, fn_g, fn_b, a_ln);
    gemm256_bt_kernel<<<(CHUNK / 256) * (kDIM / 256), 512, 0, stream>>>(
        (const unsigned short*)a_ln, (const unsigned short*)vp_w_t, vp_b,
        v + (size_t)c * CHUNK * kDIM, kDIM / 256);
  }

  // phase B
  ln_bf16_kernel<<<NROWQ / 8, 256, 0, stream>>>(query, qn_g, qn_b, q_ln);
  gemm_bt_kernel<2, kDIM><<<dim3(kOAW / 128, NROWQ / 128), 256, 0, stream>>>(
      (const unsigned short*)q_ln, (const unsigned short*)oa_wt, oa_bias,
      nullptr, nullptr, nullptr, oa_raw);
  aw_softmax_kernel<<<(NROWQ * kHEADS) / 256, 256, 0, stream>>>(oa_raw);
  sample_kernel<<<NROWQ / 2, 192, 0, stream>>>(oa_raw, refp, v, samp);
  gemm_bt_kernel<1, kDIM><<<dim3(kDIM / 128, NROWQ / 128), 256, 0, stream>>>(
      (const unsigned short*)samp, (const unsigned short*)op_w_t, op_b,
      nullptr, q_ln, query, x);

  // phase C: FFN, all matmuls via MFMA
  ln_bf16_kernel<<<NROWQ / 8, 256, 0, stream>>>(x, ffn_g, ffn_b, x_ln);
  gemm_bt_kernel<2, kDIM><<<dim3(kOAW / 128, NROWQ / 128), 256, 0, stream>>>(
      (const unsigned short*)x_ln, (const unsigned short*)fc1_wt, fc1_bp,
      nullptr, nullptr, nullptr, y1p);
  dwconv_gelu_kernel<<<(NROWQ * kHID) / 256, 256, 0, stream>>>(y1p, dw_w, dw_b, y2);
  gemm_bt_kernel<3, kHID><<<dim3(kDIM / 128, NROWQ / 128), 256, 0, stream>>>(
      (const unsigned short*)y2, (const unsigned short*)fc2_wt, fc2_b,
      nullptr, nullptr, x, (float*)d_out);
}